// Round 2
// 627.900 us; speedup vs baseline: 1.3126x; 1.3126x over previous
//
#include <hip/hip_runtime.h>
#include <math.h>
#include <stdint.h>

#define BB 4
#define TT 8
#define CC 128
#define HWW 9216            // 96*96
#define NPG 1179648.0f      // C*H*W per (b,t) group
#define EPS 1e-5f
#define SCALE 0.17677669529663687f   // 1/sqrt(32)

// ws layout in floats: sums[64] | A[32][128] | B[32][128]
#define WS_SUMS 0
#define WS_A    64
#define WS_B    4160

typedef __attribute__((ext_vector_type(4))) float f32x4;

// direct global->LDS, 16B per lane; HW writes lds_base + lane*16.
// NOTE: casts must be direct pointer casts (addrspacecast), NOT via uintptr_t —
// the integer round-trip reinterprets the flat address as an LDS offset.
__device__ __forceinline__ void gload16(const float* g, float* l) {
    __builtin_amdgcn_global_load_lds(
        (const __attribute__((address_space(1))) void*)g,
        (__attribute__((address_space(3))) void*)l,
        16, 0, 0);
}

__global__ __launch_bounds__(256) void stats_kernel(
    const float* __restrict__ x, const float* __restrict__ pe,
    float* __restrict__ sums)
{
    const int g    = blockIdx.y;
    const int part = blockIdx.x;
    const int tid  = threadIdx.x;
    const int t    = g & 7;
    float s1 = 0.f, s2 = 0.f;
    for (int r = 0; r < 8; ++r) {
        const int c = part * 8 + r;
        const float pec = pe[t * CC + c];
        const float4* row = (const float4*)(x + ((size_t)g * CC + c) * HWW);
        for (int i = tid; i < HWW / 4; i += 256) {
            float4 v = row[i];
            float a = v.x + pec, b = v.y + pec, cc2 = v.z + pec, d = v.w + pec;
            s1 += (a + b) + (cc2 + d);
            s2 += (a * a + b * b) + (cc2 * cc2 + d * d);
        }
    }
    for (int off = 32; off; off >>= 1) {
        s1 += __shfl_down(s1, off);
        s2 += __shfl_down(s2, off);
    }
    __shared__ float red[8];
    const int wid = tid >> 6, lane = tid & 63;
    if (lane == 0) { red[wid] = s1; red[4 + wid] = s2; }
    __syncthreads();
    if (tid == 0) {
        atomicAdd(&sums[g * 2 + 0], red[0] + red[1] + red[2] + red[3]);
        atomicAdd(&sums[g * 2 + 1], red[4] + red[5] + red[6] + red[7]);
    }
}

__global__ void finalize_kernel(
    const float* __restrict__ pe, const float* __restrict__ nw,
    const float* __restrict__ nb, float* ws)
{
    const int g = blockIdx.x;
    const int c = threadIdx.x;
    const float inv = 1.0f / NPG;
    const float mean = ws[WS_SUMS + g * 2 + 0] * inv;
    const float var  = ws[WS_SUMS + g * 2 + 1] * inv - mean * mean;
    const float rstd = rsqrtf(var + EPS);
    const int t = g & 7;
    const float a = rstd * nw[c];
    ws[WS_A + g * CC + c] = a;
    ws[WS_B + g * CC + c] = (pe[t * CC + c] - mean) * a + nb[c];
}

// Fused attention, rank-32 factorized, two passes over the (L2/LLC-hot) tiles:
//   pass 1: q7 = Wq_n xn7 -> u = Wk_n^T q7 (u[32]/thread) -> 8 scores -> softmax wts
//   pass 2: restream tiles, xb[32] += wt[t]*xn_t -> v = Wv_n xb -> y = P v -> out
// 1024 threads = 16 waves, wave = (head n = w>>2, quarter hq = w&3), lane = position.
// Normalization folded at read: xn_norm = A[g][c]*xraw + B[g][c] (A,B wave-uniform).
// __launch_bounds__(1024, 4): 128-VGPR cap — guaranteed spill-free. If natural
// allocation lands <=64 we get 2 blocks/CU anyway (cap, not reservation).
__global__ __launch_bounds__(1024, 4) void fused2_kernel(
    const float* __restrict__ x, const float* __restrict__ ws,
    const float* __restrict__ qkv_w, const float* __restrict__ proj_w,
    float* __restrict__ out)
{
    __shared__ __align__(16) float xn[CC][64];   // 32 KB: raw x tile [c][pos]
    __shared__ __align__(16) float vq[CC][64];   // 32 KB: q7 exchange, later v buffer
    __shared__ float sbuf[16][64];               // 4 KB: score quarter-partials

    const int tid  = threadIdx.x;
    const int lane = tid & 63;                  // position
    const int w    = tid >> 6;                  // wave 0..15
    const int n    = __builtin_amdgcn_readfirstlane(w >> 2);   // head
    const int hq   = __builtin_amdgcn_readfirstlane(w & 3);    // quarter
    const int b    = blockIdx.y;
    const int hw0  = blockIdx.x * 64;

    const float* A = ws + WS_A;
    const float* B = ws + WS_B;

    const int rsub = lane >> 4;                 // 0..3 (row within 4-row group)
    const int coff = (lane & 15) * 4;           // float col within row

    // stage tile t: wave w loads rows w*8 .. w*8+7 (2 x global_load_lds dwordx4)
    auto stage = [&](int t) {
        const size_t gb = (size_t)((b * TT + t) * CC) * HWW + hw0 + coff;
        #pragma unroll
        for (int k = 0; k < 2; ++k) {
            const int r0 = w * 8 + k * 4;
            gload16(x + gb + (size_t)(r0 + rsub) * HWW, &xn[r0][0]);
        }
    };

    // ---- stage t=7, compute q7 partial (8 d-rows, all 128 c) ----
    stage(7);
    __syncthreads();

    const int g7 = b * TT + 7;
    const float* A7 = A + g7 * CC;
    const float* B7 = B + g7 * CC;
    {
        const float* Wq = qkv_w + (n * 32 + hq * 8) * CC;
        float q7[8] = {0.f,0.f,0.f,0.f,0.f,0.f,0.f,0.f};
        for (int c0 = 0; c0 < CC; c0 += 8) {
            float xv[8];
            #pragma unroll
            for (int i = 0; i < 8; ++i)
                xv[i] = fmaf(xn[c0 + i][lane], A7[c0 + i], B7[c0 + i]);
            #pragma unroll
            for (int d = 0; d < 8; ++d) {
                #pragma unroll
                for (int i = 0; i < 8; ++i)
                    q7[d] = fmaf(Wq[d * CC + c0 + i], xv[i], q7[d]);
            }
        }
        #pragma unroll
        for (int d = 0; d < 8; ++d)
            vq[n * 32 + hq * 8 + d][lane] = q7[d];
    }
    __syncthreads();

    // ---- u[32] = Wk_n^T q7 (j-slice = hq*32..hq*32+31) ----
    float u[32];
    #pragma unroll
    for (int j = 0; j < 32; ++j) u[j] = 0.f;
    {
        const float* Wk = qkv_w + (CC + n * 32) * CC + hq * 32;
        for (int d = 0; d < 32; ++d) {
            const float qv = vq[n * 32 + d][lane];
            #pragma unroll
            for (int j = 0; j < 32; ++j)
                u[j] = fmaf(Wk[d * CC + j], qv, u[j]);
        }
    }

    // ---- scores: t=7 from resident tile, then t=0..6 ----
    float sreg[8];
    auto score_tile = [&](int t) {
        const float* At = A + (b * TT + t) * CC + hq * 32;
        const float* Bt = B + (b * TT + t) * CC + hq * 32;
        float s0 = 0.f, s1 = 0.f, s2 = 0.f, s3 = 0.f;
        #pragma unroll
        for (int j = 0; j < 32; j += 4) {
            float x0 = fmaf(xn[hq * 32 + j + 0][lane], At[j + 0], Bt[j + 0]);
            float x1 = fmaf(xn[hq * 32 + j + 1][lane], At[j + 1], Bt[j + 1]);
            float x2 = fmaf(xn[hq * 32 + j + 2][lane], At[j + 2], Bt[j + 2]);
            float x3 = fmaf(xn[hq * 32 + j + 3][lane], At[j + 3], Bt[j + 3]);
            s0 = fmaf(u[j + 0], x0, s0);
            s1 = fmaf(u[j + 1], x1, s1);
            s2 = fmaf(u[j + 2], x2, s2);
            s3 = fmaf(u[j + 3], x3, s3);
        }
        sbuf[w][lane] = (s0 + s1) + (s2 + s3);
    };

    score_tile(7);
    __syncthreads();
    sreg[7] = (sbuf[n * 4 + 0][lane] + sbuf[n * 4 + 1][lane]) +
              (sbuf[n * 4 + 2][lane] + sbuf[n * 4 + 3][lane]);

    #pragma unroll            // forced: sreg[t] must be statically indexed
    for (int t = 0; t < 7; ++t) {
        stage(t);                 // safe: all waves passed post-score barrier
        __syncthreads();          // drains gload vmcnt; tile ready
        score_tile(t);
        __syncthreads();          // sbuf writes visible
        sreg[t] = (sbuf[n * 4 + 0][lane] + sbuf[n * 4 + 1][lane]) +
                  (sbuf[n * 4 + 2][lane] + sbuf[n * 4 + 3][lane]);
    }

    // ---- softmax over 8 scores -> final weights (invl folded in) ----
    float m = fmaxf(fmaxf(fmaxf(sreg[0], sreg[1]), fmaxf(sreg[2], sreg[3])),
                    fmaxf(fmaxf(sreg[4], sreg[5]), fmaxf(sreg[6], sreg[7])));
    float wt[8];
    float l = 0.f;
    #pragma unroll
    for (int t = 0; t < 8; ++t) { wt[t] = __expf((sreg[t] - m) * SCALE); l += wt[t]; }
    const float invl = 1.0f / l;
    #pragma unroll
    for (int t = 0; t < 8; ++t) wt[t] *= invl;

    // ---- pass 2: restream tiles (L2/LLC-hot), accumulate xbar quarter ----
    float xb[32];
    #pragma unroll
    for (int j = 0; j < 32; ++j) xb[j] = 0.f;
    #pragma unroll            // forced: wt[t] must be statically indexed
    for (int t = 0; t < 8; ++t) {
        __syncthreads();          // all reads of previous tile done
        stage(t);
        __syncthreads();          // tile ready
        const float* At = A + (b * TT + t) * CC + hq * 32;
        const float* Bt = B + (b * TT + t) * CC + hq * 32;
        const float wc = wt[t];
        #pragma unroll
        for (int j = 0; j < 32; ++j) {
            float xv = fmaf(xn[hq * 32 + j][lane], At[j], Bt[j]);
            xb[j] = fmaf(xv, wc, xb[j]);
        }
    }

    // ---- v_n[d] = sum_c Wv_n[d][c] * xbar_n[c]: quarter-partials reduced in vq ----
    {
        const float* Wv = qkv_w + (2 * CC + n * 32) * CC + hq * 32;
        #pragma unroll
        for (int r = 0; r < 4; ++r) {
            if (hq == r) {        // wave-uniform branch (hq is readfirstlane'd)
                for (int d0 = 0; d0 < 32; d0 += 8) {
                    float vp[8];
                    #pragma unroll
                    for (int d = 0; d < 8; ++d) {
                        float s0 = 0.f, s1 = 0.f, s2 = 0.f, s3 = 0.f;
                        const float* Wr = Wv + (d0 + d) * CC;
                        #pragma unroll
                        for (int c = 0; c < 32; c += 4) {
                            s0 = fmaf(Wr[c + 0], xb[c + 0], s0);
                            s1 = fmaf(Wr[c + 1], xb[c + 1], s1);
                            s2 = fmaf(Wr[c + 2], xb[c + 2], s2);
                            s3 = fmaf(Wr[c + 3], xb[c + 3], s3);
                        }
                        vp[d] = (s0 + s1) + (s2 + s3);
                    }
                    if (r == 0) {
                        #pragma unroll
                        for (int d = 0; d < 8; ++d)
                            vq[n * 32 + d0 + d][lane] = vp[d];
                    } else {
                        #pragma unroll
                        for (int d = 0; d < 8; ++d)
                            vq[n * 32 + d0 + d][lane] += vp[d];
                    }
                }
            }
            __syncthreads();      // barrier outside the conditional: uniform
        }
    }

    // ---- y[e] = sum_nd P[e][nd] * v[nd], e-slice = w*8..w*8+7, direct store ----
    float y[8];
    #pragma unroll
    for (int e = 0; e < 8; ++e) y[e] = 0.f;
    for (int c0 = 0; c0 < CC; c0 += 16) {
        float vv[16];
        #pragma unroll
        for (int i = 0; i < 16; ++i) vv[i] = vq[c0 + i][lane];
        #pragma unroll
        for (int e = 0; e < 8; ++e) {
            const float* Pr = proj_w + (w * 8 + e) * CC + c0;
            #pragma unroll
            for (int i = 0; i < 16; ++i)
                y[e] = fmaf(Pr[i], vv[i], y[e]);
        }
    }
    const size_t ob = (size_t)(b * CC + w * 8) * HWW + hw0 + lane;
    #pragma unroll
    for (int e = 0; e < 8; ++e)
        out[ob + (size_t)e * HWW] = y[e];
}

extern "C" void kernel_launch(void* const* d_in, const int* in_sizes, int n_in,
                              void* d_out, int out_size, void* d_ws, size_t ws_size,
                              hipStream_t stream) {
    const float* x      = (const float*)d_in[0];
    const float* pe     = (const float*)d_in[1];
    const float* nw     = (const float*)d_in[2];
    const float* nb     = (const float*)d_in[3];
    const float* qkv_w  = (const float*)d_in[4];
    const float* proj_w = (const float*)d_in[5];
    float* out = (float*)d_out;
    float* ws  = (float*)d_ws;

    hipMemsetAsync(ws, 0, 64 * sizeof(float), stream);
    stats_kernel<<<dim3(16, 32), 256, 0, stream>>>(x, pe, ws);
    finalize_kernel<<<32, 128, 0, stream>>>(pe, nw, nb, ws);
    fused2_kernel<<<dim3(HWW / 64, BB), 1024, 0, stream>>>(x, ws, qkv_w, proj_w, out);
}